// Round 8
// baseline (2617.246 us; speedup 1.0000x reference)
//
#include <hip/hip_runtime.h>
#include <math.h>

#define BATCH 1024
#define TSEQ  2048
#define DIN   5
#define H     64
#define BT    4      // elems per pair; 256 pairs = 512 blocks
#define SSTR  144    // halves/elem: [h1 64 | h2 64 | pad 16] -> exact 2-way banks (free)
#define NOUT  128
#define RING_D 128   // y1 ring depth (steps); 512B/step/pair -> 16 MB workspace
#define CHK   16     // flag publish granularity (steps)

typedef _Float16 f16x8 __attribute__((ext_vector_type(8)));
typedef float    f32x4 __attribute__((ext_vector_type(4)));

#if __has_builtin(__builtin_amdgcn_rcpf)
__device__ __forceinline__ float rcp_fast(float x) { return __builtin_amdgcn_rcpf(x); }
#else
__device__ __forceinline__ float rcp_fast(float x) { return 1.0f / x; }
#endif

#define LOG2E 1.44269504088896f
#define MFMA16(A, B, C) __builtin_amdgcn_mfma_f32_16x16x32_f16((A), (B), (C), 0, 0, 0)

__device__ __forceinline__ float sigm2(float s) {   // s = log2e * p
    return rcp_fast(1.0f + __builtin_amdgcn_exp2f(-s));
}
__device__ __forceinline__ float tanh2(float s) {   // s = 2*log2e * p
    return fmaf(-2.0f, rcp_fast(__builtin_amdgcn_exp2f(s) + 1.0f), 1.0f);
}

// lgkm-only barrier: ds_write visibility without draining vmcnt.
__device__ __forceinline__ void sync_lgkm() {
    asm volatile("s_waitcnt lgkmcnt(0)" ::: "memory");
    __builtin_amdgcn_s_barrier();
    asm volatile("" ::: "memory");
}

// R8: SPLIT BARRIER DOMAINS. R0-R7 established the per-step wall (~1270cyc)
// = barrier ~250 (measured R7) + LDS RT ~300 + MFMA 384 + gates ~200, summed
// because one block = one barrier domain = all 8 waves lockstep on the same
// pipes. Fix: producer block (4 waves, layer-1, own per-step barrier for the
// h1 exchange) + consumer block (4 waves, layer-2+FC, own barrier for h2),
// paired by a GLOBAL y1 ring. y1 is forward-only -> deep lag is free: flags
// publish every CHK=16 steps (device-scope release/acquire), ring 128 deep
// with back-pressure. Two co-resident blocks per CU have independent
// barriers -> phases drift/overlap naturally (the R7 stagger, zero extra
// barriers). Consumer prefetches y1(t+1) to regs 1 step ahead and issues
// its y1-MFMAs PRE-barrier, so its post-barrier chain = read h2 + 8 MFMA +
// gates + write.
// Deadlock-freedom: 512 blocks, launch_bounds(256,2), 4KB LDS -> all blocks
// co-resident (2/CU). Producer@t needs cons >= t-127 (consumer is at most
// 127+16 behind its published flag); consumer@t needs prod >= t+2 (producer
// publishes >= 16*floor(own_t/16), runs ahead). If producer blocked at t,
// consumer is at c <= t-112 and needs flag >= c+2 <= t-110 <= published ->
// consumer runs. No cycle.
__global__ __launch_bounds__(256, 2)
void lstm_pair(const float* __restrict__ x,
               const float* __restrict__ Wih0, const float* __restrict__ Whh0,
               const float* __restrict__ bih0, const float* __restrict__ bhh0,
               const float* __restrict__ Wih1, const float* __restrict__ Whh1,
               const float* __restrict__ bih1, const float* __restrict__ bhh1,
               const float* __restrict__ Wfc,  const float* __restrict__ bfc,
               float* __restrict__ out,
               int* __restrict__ pflag, int* __restrict__ cflag,
               _Float16* __restrict__ ring)
{
    __shared__ alignas(16) _Float16 S[2][BT * SSTR];   // 2.25 KB state, double-buffered
    __shared__ alignas(16) float    h2f[BT][H];        // 1 KB final h2 for FC (consumer)

    const int tid  = threadIdx.x;
    const int w    = tid >> 6;         // 0..3
    const int lane = tid & 63;
    const int col  = lane & 15;        // n (h-unit offset); A-row m
    const int q    = lane >> 4;        // quad -> C/D row group; k-slice
    const int hu   = 16 * w + col;
    const int p    = blockIdx.x >> 1;  // pair id (elems 4p..4p+3)
    const int role = blockIdx.x & 1;   // 0 = layer-1 producer, 1 = layer-2 consumer
    const int b0   = p * BT;

    _Float16* rp = ring + (size_t)p * (RING_D * BT * H);   // pair's y1 ring

    // ---- zero state buffers ----
    for (int j = tid; j < 2 * BT * SSTR; j += 256)
        ((_Float16*)S)[j] = (_Float16)0.0f;

    const float sgl[4] = {LOG2E, LOG2E, 2.0f * LOG2E, LOG2E};  // i,f,g,o

    const int ab  = (col >> 2) * SSTR + q * 8;   // A-frag read base (halves)
    const int wb1 = q * SSTR + hu;               // h1 write slot
    const int wb2 = q * SSTR + 64 + hu;          // h2 write slot

    if (role == 0) {
        // ==================== PRODUCER: layer-1 ====================
        f16x8 Bf[4][2];
        float wx[4][DIN], b1s[4];
        #pragma unroll
        for (int g = 0; g < 4; ++g) {
            const int   row = g * 64 + hu;
            const float sg  = sgl[g];
            const float* wh = Whh0 + row * H;
            #pragma unroll
            for (int j = 0; j < 8; ++j) {
                const int k = q * 8 + j;
                Bf[g][0][j] = (_Float16)(wh[k]      * sg);
                Bf[g][1][j] = (_Float16)(wh[32 + k] * sg);
            }
            #pragma unroll
            for (int j = 0; j < DIN; ++j)
                wx[g][j] = Wih0[row * DIN + j] * sg;
            b1s[g] = (bih0[row] + bhh0[row]) * sg;
        }

        // x pipeline: dxs(t) ready at step t; regs carry x(t+1)
        const float* xq = x + (size_t)(b0 + q) * TSEQ * DIN;
        float x0, x1, x2, x3, x4;
        float dxs[4];
        {
            float a0 = xq[0], a1 = xq[1], a2 = xq[2], a3 = xq[3], a4 = xq[4];
            #pragma unroll
            for (int g = 0; g < 4; ++g) {
                float s = fmaf(a0, wx[g][0], b1s[g]);
                s = fmaf(a1, wx[g][1], s);
                s = fmaf(a2, wx[g][2], s);
                s = fmaf(a3, wx[g][3], s);
                dxs[g] = fmaf(a4, wx[g][4], s);
            }
            x0 = xq[DIN + 0]; x1 = xq[DIN + 1]; x2 = xq[DIN + 2];
            x3 = xq[DIN + 3]; x4 = xq[DIN + 4];
            xq += 2 * DIN;
        }

        float cst = 0.0f;
        int consf = 0;
        __syncthreads();

        #pragma unroll 1
        for (int t = 0; t < TSEQ; ++t) {
            // back-pressure: slot t&127 holds y1(t-128), consumer must be past it
            if (t >= RING_D) {
                const int need = t - RING_D + 1;
                while (consf < need) {
                    consf = __hip_atomic_load(cflag + p, __ATOMIC_RELAXED,
                                              __HIP_MEMORY_SCOPE_AGENT);
                    if (consf >= need) break;
                    __builtin_amdgcn_s_sleep(8);
                }
            }

            const bool ld2 = (t + 2 < TSEQ);
            float n0, n1, n2, n3, n4;
            if (ld2) { n0 = xq[0]; n1 = xq[1]; n2 = xq[2]; n3 = xq[3]; n4 = xq[4]; xq += DIN; }

            const _Float16* rb = S[(t + 1) & 1];
            f16x8 a0 = *(const f16x8*)&rb[ab];        // h1(t-1) k 0..31
            f16x8 a1 = *(const f16x8*)&rb[ab + 32];   // h1(t-1) k 32..63

            f32x4 d[4];
            __builtin_amdgcn_s_setprio(1);
            #pragma unroll
            for (int g = 0; g < 4; ++g) {
                f32x4 c0 = {dxs[g], 0.f, 0.f, 0.f};
                d[g] = MFMA16(a0, Bf[g][0], c0);
                d[g] = MFMA16(a1, Bf[g][1], d[g]);
            }
            __builtin_amdgcn_s_setprio(0);

            float iv = sigm2(d[0][0]);
            float fv = sigm2(d[1][0]);
            float gv = tanh2(d[2][0]);
            float ov = sigm2(d[3][0]);
            cst = fmaf(fv, cst, iv * gv);
            const float hval = ov * tanh2(2.0f * LOG2E * cst);

            if (t + 1 < TSEQ) {   // dxs(t+1) off the critical path
                #pragma unroll
                for (int g = 0; g < 4; ++g) {
                    float s = fmaf(x0, wx[g][0], b1s[g]);
                    s = fmaf(x1, wx[g][1], s);
                    s = fmaf(x2, wx[g][2], s);
                    s = fmaf(x3, wx[g][3], s);
                    dxs[g] = fmaf(x4, wx[g][4], s);
                }
            }
            if (ld2) { x0 = n0; x1 = n1; x2 = n2; x3 = n3; x4 = n4; }

            const _Float16 hv16 = (_Float16)hval;
            S[t & 1][wb1] = hv16;                                   // own recurrence
            rp[((t & (RING_D - 1)) * BT + q) * H + hu] = hv16;      // y1 -> ring

            if ((t & (CHK - 1)) == CHK - 1) {
                asm volatile("s_waitcnt vmcnt(0)" ::: "memory");    // ring stores done
                sync_lgkm();
                if (tid == 0)
                    __hip_atomic_store(pflag + p, t + 1, __ATOMIC_RELEASE,
                                       __HIP_MEMORY_SCOPE_AGENT);
            } else {
                sync_lgkm();
            }
        }
    } else {
        // ==================== CONSUMER: layer-2 + FC ====================
        f16x8 Bf[4][4];   // [g][0..1]=Wih1 k-halves  [g][2..3]=Whh1 k-halves
        f32x4 bC[4];
        #pragma unroll
        for (int g = 0; g < 4; ++g) {
            const int   row = g * 64 + hu;
            const float sg  = sgl[g];
            const float* wa = Wih1 + row * H;
            const float* wb = Whh1 + row * H;
            #pragma unroll
            for (int j = 0; j < 8; ++j) {
                const int k = q * 8 + j;
                Bf[g][0][j] = (_Float16)(wa[k]      * sg);
                Bf[g][1][j] = (_Float16)(wa[32 + k] * sg);
                Bf[g][2][j] = (_Float16)(wb[k]      * sg);
                Bf[g][3][j] = (_Float16)(wb[32 + k] * sg);
            }
            const float bb = (bih1[row] + bhh1[row]) * sg;
            bC[g] = f32x4{bb, bb, bb, bb};
        }

        float cst = 0.0f, h2fin = 0.0f;
        int pf = 0;
        const int yoff = (col >> 2) * H + q * 8;   // y1 A-frag offset in a slot

        __syncthreads();

        // wait for y1(0), load it
        while (pf < 1) {
            pf = __hip_atomic_load(pflag + p, __ATOMIC_ACQUIRE, __HIP_MEMORY_SCOPE_AGENT);
            if (pf >= 1) break;
            __builtin_amdgcn_s_sleep(8);
        }
        f16x8 cy0 = *(const f16x8*)&rp[yoff];
        f16x8 cy1 = *(const f16x8*)&rp[yoff + 32];

        #pragma unroll 1
        for (int t = 0; t < TSEQ; ++t) {
            // prefetch y1(t+1) (poll flag only when shadow is stale)
            f16x8 ny0, ny1;
            const bool pre = (t + 1 < TSEQ);
            if (pre) {
                if (pf < t + 2) {
                    while (pf < t + 2) {
                        pf = __hip_atomic_load(pflag + p, __ATOMIC_ACQUIRE,
                                               __HIP_MEMORY_SCOPE_AGENT);
                        if (pf >= t + 2) break;
                        __builtin_amdgcn_s_sleep(8);
                    }
                }
                const int so = ((t + 1) & (RING_D - 1)) * (BT * H);
                ny0 = *(const f16x8*)&rp[so + yoff];
                ny1 = *(const f16x8*)&rp[so + yoff + 32];
            }

            // y1-part MFMAs: independent of h2 exchange -> pre-barrier
            f32x4 e[4];
            __builtin_amdgcn_s_setprio(1);
            #pragma unroll
            for (int g = 0; g < 4; ++g) {
                e[g] = MFMA16(cy0, Bf[g][0], bC[g]);
                e[g] = MFMA16(cy1, Bf[g][1], e[g]);
            }
            __builtin_amdgcn_s_setprio(0);

            sync_lgkm();   // h2(t-1) written last iter now visible

            // consumed-through flag (ordered by the barrier above)
            if ((t & (CHK - 1)) == 0 && t > 0 && tid == 0)
                __hip_atomic_store(cflag + p, t, __ATOMIC_RELAXED,
                                   __HIP_MEMORY_SCOPE_AGENT);

            const _Float16* rb = S[(t + 1) & 1];
            f16x8 ah0 = *(const f16x8*)&rb[ab + 64];   // h2(t-1) k 0..31
            f16x8 ah1 = *(const f16x8*)&rb[ab + 96];   // h2(t-1) k 32..63

            f32x4 f[4];
            const f32x4 z4 = {0.f, 0.f, 0.f, 0.f};
            __builtin_amdgcn_s_setprio(1);
            #pragma unroll
            for (int g = 0; g < 4; ++g) {
                f[g] = MFMA16(ah0, Bf[g][2], z4);
                f[g] = MFMA16(ah1, Bf[g][3], f[g]);
            }
            __builtin_amdgcn_s_setprio(0);

            float p0 = e[0][0] + f[0][0];
            float p1 = e[1][0] + f[1][0];
            float p2 = e[2][0] + f[2][0];
            float p3 = e[3][0] + f[3][0];
            float iv = sigm2(p0);
            float fv = sigm2(p1);
            float gv = tanh2(p2);
            float ov = sigm2(p3);
            cst = fmaf(fv, cst, iv * gv);
            h2fin = ov * tanh2(2.0f * LOG2E * cst);
            S[t & 1][wb2] = (_Float16)h2fin;

            if (pre) { cy0 = ny0; cy1 = ny1; }
        }

        // -------- epilogue: out = relu(h2(T-1) @ Wfc^T + bfc) --------
        h2f[q][hu] = h2fin;
        __syncthreads();
        {
            const int o  = tid & (NOUT - 1);   // 0..127
            const int eh = tid >> 7;           // 0..1 -> elems {eh, eh+2}
            const float4* wr = (const float4*)(Wfc + o * H);
            #pragma unroll
            for (int e2 = eh; e2 < BT; e2 += 2) {
                const float* hv = h2f[e2];
                float s0 = 0.f, s1 = 0.f, s2 = 0.f, s3 = 0.f;
                #pragma unroll
                for (int k = 0; k < H / 4; ++k) {
                    float4 wv = wr[k];
                    s0 = fmaf(wv.x, hv[4 * k + 0], s0);
                    s1 = fmaf(wv.y, hv[4 * k + 1], s1);
                    s2 = fmaf(wv.z, hv[4 * k + 2], s2);
                    s3 = fmaf(wv.w, hv[4 * k + 3], s3);
                }
                float acc = bfc[o] + (s0 + s1) + (s2 + s3);
                out[(size_t)(b0 + e2) * NOUT + o] = fmaxf(acc, 0.0f);
            }
        }
    }
}

extern "C" void kernel_launch(void* const* d_in, const int* in_sizes, int n_in,
                              void* d_out, int out_size, void* d_ws, size_t ws_size,
                              hipStream_t stream) {
    const float* x    = (const float*)d_in[0];
    const float* Wih0 = (const float*)d_in[1];
    const float* Whh0 = (const float*)d_in[2];
    const float* bih0 = (const float*)d_in[3];
    const float* bhh0 = (const float*)d_in[4];
    const float* Wih1 = (const float*)d_in[5];
    const float* Whh1 = (const float*)d_in[6];
    const float* bih1 = (const float*)d_in[7];
    const float* bhh1 = (const float*)d_in[8];
    const float* Wfc  = (const float*)d_in[9];
    const float* bfc  = (const float*)d_in[10];
    float* out = (float*)d_out;

    // ws layout: [0,1KB) pflag[256] | [1KB,2KB) cflag[256] | [4KB, +16MB) y1 ring
    int*      pflag = (int*)d_ws;
    int*      cflag = (int*)d_ws + 256;
    _Float16* ring  = (_Float16*)((char*)d_ws + 4096);

    hipMemsetAsync(d_ws, 0, 2048, stream);   // zero both flag arrays (graph-capturable)

    lstm_pair<<<dim3(2 * (BATCH / BT)), dim3(256), 0, stream>>>(
        x, Wih0, Whh0, bih0, bhh0, Wih1, Whh1, bih1, bhh1, Wfc, bfc, out,
        pflag, cflag, ring);
}

// Round 9
// 978.575 us; speedup vs baseline: 2.6745x; 2.6745x over previous
//
#include <hip/hip_runtime.h>
#include <math.h>

#define BATCH 1024
#define TSEQ  2048
#define DIN   5
#define H     64
#define BT    4      // elems per block; grid 256 = every CU
#define SSTR  144    // halves/elem: [h1 64 | h2 64 | pad 16] = 72 words -> exact 2-way banks (free)
#define NOUT  128

typedef _Float16 f16x8 __attribute__((ext_vector_type(8)));
typedef float    f32x4 __attribute__((ext_vector_type(4)));

#if __has_builtin(__builtin_amdgcn_rcpf)
__device__ __forceinline__ float rcp_fast(float x) { return __builtin_amdgcn_rcpf(x); }
#else
__device__ __forceinline__ float rcp_fast(float x) { return 1.0f / x; }
#endif

#define LOG2E 1.44269504088896f

// exp2-based activations; weights/biases pre-scaled by log2e (sigmoid) or
// 2*log2e (tanh gate) so no per-use multiply.
__device__ __forceinline__ float sigm2(float s) {   // s = log2e * p
    return rcp_fast(1.0f + __builtin_amdgcn_exp2f(-s));
}
__device__ __forceinline__ float tanh2(float s) {   // s = 2*log2e * p
    return fmaf(-2.0f, rcp_fast(__builtin_amdgcn_exp2f(s) + 1.0f), 1.0f);
}

// r8 skeleton (512 thr = 8 waves, BT=4, grid 256, layer-split waves, barrier)
// with the critical chain shortened:
//  - x lives in REGISTERS (global->reg prefetch), not LDS; its MFMA
//    contribution dx[g] = mfma(ax, Bx[g], bias) is precomputed one iter early
//    -> lay-1 post-barrier chain is ds_read + 2 MFMAs + gates.
//  - state = [h1|h2] only, stride 144 halves: all b128 reads exact 2-way.
//  - loop-invariant lane addresses hoisted; no ring arithmetic.
// A = state with elem = m>>2 -> D reg 0 is elem q for every lane (no selects).
// NOTE (R1-R8 campaign): every structural variant tried from this base —
// merged-layer waves (1/SIMD), lgkm-only barrier, VALU x-proj, chain
// splitting, LDS flag-poll decoupling, e-offload rebalance, two-phase
// barrier skew, split producer/consumer blocks with a global y1 ring —
// measured neutral or worse. The per-step wall (~1270 cyc) is a
// barrier-locked latency floor: barrier ~250 + LDS RT ~300 + MFMA burst
// ~450 + gate chain ~200. This kernel is the measured optimum.
__global__ __launch_bounds__(512)
void lstm_mfma(const float* __restrict__ x,
               const float* __restrict__ Wih0, const float* __restrict__ Whh0,
               const float* __restrict__ bih0, const float* __restrict__ bhh0,
               const float* __restrict__ Wih1, const float* __restrict__ Whh1,
               const float* __restrict__ bih1, const float* __restrict__ bhh1,
               const float* __restrict__ Wfc,  const float* __restrict__ bfc,
               float* __restrict__ out)
{
    __shared__ alignas(16) _Float16 S[2][BT * SSTR];   // 2.25 KB state, double-buffered
    __shared__ alignas(16) float    h2f[BT][H];        // 1 KB final h2 for FC

    const int tid  = threadIdx.x;
    const int w    = tid >> 6;         // 0..7
    const int lane = tid & 63;
    const int col  = lane & 15;        // n (h-unit offset); A-row m
    const int q    = lane >> 4;        // quad -> G elem; k-slice
    const int ww   = w & 3;            // h-unit tile
    const int lay  = w >> 2;           // 0 = layer-1, 1 = layer-2
    const int hu   = 16 * ww + col;
    const int b0   = blockIdx.x * BT;

    // ---- zero both state buffers ----
    for (int j = tid; j < 2 * BT * SSTR; j += 512)
        ((_Float16*)S)[j] = (_Float16)0.0f;

    const float sgl[4] = {LOG2E, LOG2E, 2.0f * LOG2E, LOG2E};  // i,f,g,o

    // ---- B-fragments for THIS wave's layer (registers, pre-scaled) ----
    // B[k=q*8+j][n=col]; n-tile g = gate rows g*64 + hu.
    // lay0: [0]=Whh0 k0-31 [1]=Whh0 k32-63 [2]=Wih0 (5 of 32; zero for q!=0) [3]=0
    // lay1: [0]=Wih1 k0-31 [1]=Wih1 k32-63 [2]=Whh1 k0-31 [3]=Whh1 k32-63
    f16x8 Bf[4][4];
    f32x4 bC[4];
    #pragma unroll
    for (int g = 0; g < 4; ++g) {
        const int   row = g * 64 + hu;
        const float sg  = sgl[g];
        const float* Wa = lay ? (Wih1 + row * H) : (Whh0 + row * H);
        f16x8 f0, f1, f2, f3;
        #pragma unroll
        for (int j = 0; j < 8; ++j) {
            f0[j] = (_Float16)(Wa[q * 8 + j] * sg);
            f1[j] = (_Float16)(Wa[32 + q * 8 + j] * sg);
        }
        if (lay) {
            const float* Wb = Whh1 + row * H;
            #pragma unroll
            for (int j = 0; j < 8; ++j) {
                f2[j] = (_Float16)(Wb[q * 8 + j] * sg);
                f3[j] = (_Float16)(Wb[32 + q * 8 + j] * sg);
            }
        } else {
            #pragma unroll
            for (int j = 0; j < 8; ++j) {
                const int kk = q * 8 + j;
                f2[j] = (_Float16)(kk < DIN ? Wih0[row * DIN + kk] * sg : 0.0f);
                f3[j] = (_Float16)0.0f;
            }
        }
        Bf[g][0] = f0; Bf[g][1] = f1; Bf[g][2] = f2; Bf[g][3] = f3;
        const float bb = (lay ? (bih1[row] + bhh1[row])
                              : (bih0[row] + bhh0[row])) * sg;
        bC[g] = f32x4{bb, bb, bb, bb};
    }

    // ---- x machinery (lay-0 waves): direct global->reg, dx precomputed ----
    // Only q==0 lanes carry real x (B's k>=8 rows are zero), elem = col>>2.
    const float* xp = x + (size_t)(b0 + (col >> 2)) * TSEQ * DIN;
    f16x8 ax = {(_Float16)0.0f, (_Float16)0.0f, (_Float16)0.0f, (_Float16)0.0f,
                (_Float16)0.0f, (_Float16)0.0f, (_Float16)0.0f, (_Float16)0.0f};
    f32x4 dx[4];
    if (lay == 0) {
        if (q == 0) {   // x(t=0)
            ax[0] = (_Float16)xp[0]; ax[1] = (_Float16)xp[1];
            ax[2] = (_Float16)xp[2]; ax[3] = (_Float16)xp[3];
            ax[4] = (_Float16)xp[4];
        }
        #pragma unroll
        for (int g = 0; g < 4; ++g)
            dx[g] = __builtin_amdgcn_mfma_f32_16x16x32_f16(ax, Bf[g][2], bC[g], 0, 0, 0);
        xp += DIN;      // -> t=1
    }

    const int ab  = (col >> 2) * SSTR + q * 8;   // A-frag read base (halves)
    const int wb1 = q * SSTR + hu;               // h1 write slot
    const int wb2 = q * SSTR + 64 + hu;          // h2 write slot
    float cst = 0.0f, h2fin = 0.0f;

    __syncthreads();

    // ============ main loop: iter i = layer-1(t=i) & layer-2(t=i-1) ============
    #pragma unroll 1
    for (int i = 0; i <= TSEQ; ++i) {
        const _Float16* rb = S[(i + 1) & 1];
        _Float16*       wbuf = S[i & 1];

        if (lay == 0) {
            // fire next-x loads first (latency hidden under MFMA+G)
            const bool xld = (q == 0) && (i + 1 < TSEQ);
            float x0, x1, x2, x3, x4;
            if (xld) { x0 = xp[0]; x1 = xp[1]; x2 = xp[2]; x3 = xp[3]; x4 = xp[4]; }

            f16x8 a0 = *(const f16x8*)&rb[ab];        // h1 k 0..31
            f16x8 a1 = *(const f16x8*)&rb[ab + 32];   // h1 k 32..63
            f32x4 d[4];
            #pragma unroll
            for (int g = 0; g < 4; ++g) {             // 2-deep chain (dx has x+bias)
                d[g] = __builtin_amdgcn_mfma_f32_16x16x32_f16(a0, Bf[g][0], dx[g], 0, 0, 0);
                d[g] = __builtin_amdgcn_mfma_f32_16x16x32_f16(a1, Bf[g][1], d[g], 0, 0, 0);
            }
            if (i < TSEQ) {   // layer-1 G for t=i
                float iv = sigm2(d[0][0]);
                float fv = sigm2(d[1][0]);
                float gv = tanh2(d[2][0]);
                float ov = sigm2(d[3][0]);
                cst = fmaf(fv, cst, iv * gv);
                wbuf[wb1] = (_Float16)(ov * tanh2(2.0f * LOG2E * cst));
            }
            // prep dx for t=i+1 (off the critical path)
            if (xld) {
                ax[0] = (_Float16)x0; ax[1] = (_Float16)x1;
                ax[2] = (_Float16)x2; ax[3] = (_Float16)x3;
                ax[4] = (_Float16)x4;
            }
            #pragma unroll
            for (int g = 0; g < 4; ++g)
                dx[g] = __builtin_amdgcn_mfma_f32_16x16x32_f16(ax, Bf[g][2], bC[g], 0, 0, 0);
            xp += DIN;
        } else {
            f16x8 ay0 = *(const f16x8*)&rb[ab];        // y1(t-1) k 0..31
            f16x8 ay1 = *(const f16x8*)&rb[ab + 32];   // y1(t-1) k 32..63
            f16x8 ah0 = *(const f16x8*)&rb[ab + 64];   // h2(t-2) k 0..31
            f16x8 ah1 = *(const f16x8*)&rb[ab + 96];   // h2(t-2) k 32..63
            f32x4 d[4];
            #pragma unroll
            for (int g = 0; g < 4; ++g) {
                d[g] = __builtin_amdgcn_mfma_f32_16x16x32_f16(ay0, Bf[g][0], bC[g], 0, 0, 0);
                d[g] = __builtin_amdgcn_mfma_f32_16x16x32_f16(ay1, Bf[g][1], d[g], 0, 0, 0);
                d[g] = __builtin_amdgcn_mfma_f32_16x16x32_f16(ah0, Bf[g][2], d[g], 0, 0, 0);
                d[g] = __builtin_amdgcn_mfma_f32_16x16x32_f16(ah1, Bf[g][3], d[g], 0, 0, 0);
            }
            if (i > 0) {      // layer-2 G for t=i-1
                float iv = sigm2(d[0][0]);
                float fv = sigm2(d[1][0]);
                float gv = tanh2(d[2][0]);
                float ov = sigm2(d[3][0]);
                cst = fmaf(fv, cst, iv * gv);
                h2fin = ov * tanh2(2.0f * LOG2E * cst);
                wbuf[wb2] = (_Float16)h2fin;
            }
        }
        __syncthreads();
    }

    // ---------------- epilogue: out = relu(h2(T-1) @ Wfc^T + bfc) ----------------
    if (lay) h2f[q][hu] = h2fin;
    __syncthreads();
    {
        const int e = tid >> 7;            // 0..3
        const int o = tid & (NOUT - 1);    // 0..127
        const float4* wr = (const float4*)(Wfc + o * H);
        const float*  hv = h2f[e];
        float s0 = 0.f, s1 = 0.f, s2 = 0.f, s3 = 0.f;
        #pragma unroll
        for (int k = 0; k < H / 4; ++k) {
            float4 wv = wr[k];
            s0 = fmaf(wv.x, hv[4 * k + 0], s0);
            s1 = fmaf(wv.y, hv[4 * k + 1], s1);
            s2 = fmaf(wv.z, hv[4 * k + 2], s2);
            s3 = fmaf(wv.w, hv[4 * k + 3], s3);
        }
        float acc = bfc[o] + (s0 + s1) + (s2 + s3);
        out[(size_t)(b0 + e) * NOUT + o] = fmaxf(acc, 0.0f);
    }
}

extern "C" void kernel_launch(void* const* d_in, const int* in_sizes, int n_in,
                              void* d_out, int out_size, void* d_ws, size_t ws_size,
                              hipStream_t stream) {
    const float* x    = (const float*)d_in[0];
    const float* Wih0 = (const float*)d_in[1];
    const float* Whh0 = (const float*)d_in[2];
    const float* bih0 = (const float*)d_in[3];
    const float* bhh0 = (const float*)d_in[4];
    const float* Wih1 = (const float*)d_in[5];
    const float* Whh1 = (const float*)d_in[6];
    const float* bih1 = (const float*)d_in[7];
    const float* bhh1 = (const float*)d_in[8];
    const float* Wfc  = (const float*)d_in[9];
    const float* bfc  = (const float*)d_in[10];
    float* out = (float*)d_out;

    lstm_mfma<<<dim3(BATCH / BT), dim3(512), 0, stream>>>(
        x, Wih0, Whh0, bih0, bhh0, Wih1, Whh1, bih1, bhh1, Wfc, bfc, out);
}